// Round 8
// baseline (657.600 us; speedup 1.0000x reference)
//
#include <hip/hip_runtime.h>
#include <hip/hip_bf16.h>
#include <cstdint>
#include <cstddef>

#define N_NODES 100000
#define N_EDGES 1600000
#define NBUCK   128
#define NPB     782           // nodes per bucket; 128*782 = 100096 >= N_NODES
#define NB_E    ((N_EDGES + 4095) / 4096)   // 391 blocks, 4096 edges each

typedef __attribute__((ext_vector_type(8))) short short8;
typedef __attribute__((ext_vector_type(4))) float floatx4;

__device__ inline float bf_lo(unsigned int u) { return __uint_as_float(u << 16); }
__device__ inline float bf_hi(unsigned int u) { return __uint_as_float(u & 0xffff0000u); }
__device__ inline unsigned short f2bf(float f) {
  unsigned int u = __float_as_uint(f);
  u += 0x7fffu + ((u >> 16) & 1u);   // round-nearest-even
  return (unsigned short)(u >> 16);
}

// ---------- fp32 -> bf16 conversion, 4 elems/thread ----------
__global__ void cvt_f32_bf16(const float* __restrict__ in,
                             unsigned short* __restrict__ out, int n4) {
  int t = blockIdx.x * blockDim.x + threadIdx.x;
  if (t >= n4) return;
  float4 v = ((const float4*)in)[t];
  ushort4 o;
  o.x = f2bf(v.x); o.y = f2bf(v.y); o.z = f2bf(v.z); o.w = f2bf(v.w);
  ((ushort4*)out)[t] = o;
}

// W3 (64 x 512 fp32) -> Wcat (128 x 256 bf16): rows 0-63 = self cols, 64-127 = neigh cols
__global__ void cvt_w3cat(const float* __restrict__ W3, unsigned short* __restrict__ out) {
  int t = blockIdx.x * blockDim.x + threadIdx.x;      // 128*256/4 = 8192 threads
  if (t >= 128 * 256 / 4) return;
  int idx4 = t * 4;
  int r = idx4 >> 8, c = idx4 & 255;
  float4 v = *(const float4*)(W3 + (size_t)(r & 63) * 512 + (r >> 6) * 256 + c);
  ushort4 o;
  o.x = f2bf(v.x); o.y = f2bf(v.y); o.z = f2bf(v.z); o.w = f2bf(v.w);
  *(ushort4*)(out + (size_t)r * 256 + c) = o;
}

__device__ inline int wave_incl_scan(int v, int lane) {
#pragma unroll
  for (int off = 1; off < 64; off <<= 1) {
    int t = __shfl_up(v, off, 64);
    if (lane >= off) v += t;
  }
  return v;
}

// ---------- CSR build: bucketed counting sort (no device-scope scatter) ----------
__global__ __launch_bounds__(256)
void pass1a_kernel(const int* __restrict__ dst, int* __restrict__ bucketCount) {
  __shared__ int hist[NBUCK];
  if (threadIdx.x < NBUCK) hist[threadIdx.x] = 0;
  __syncthreads();
#pragma unroll
  for (int i = 0; i < 16; ++i) {
    int e = blockIdx.x * 4096 + i * 256 + threadIdx.x;
    if (e < N_EDGES) atomicAdd(&hist[dst[e] / NPB], 1);
  }
  __syncthreads();
  if (threadIdx.x < NBUCK) atomicAdd(&bucketCount[threadIdx.x], hist[threadIdx.x]);
}

// scanB: exclusive scan of 128 bucket counts (2 waves)
__global__ void scanB_kernel(const int* __restrict__ bucketCount,
                             int* __restrict__ bucketBase, int* __restrict__ gCursorB) {
  __shared__ int wsum[2];
  int t = threadIdx.x, lane = t & 63, wid = t >> 6;   // 128 threads
  int v = bucketCount[t];
  int incl = wave_incl_scan(v, lane);
  if (lane == 63) wsum[wid] = incl;
  __syncthreads();
  int off = (wid == 1) ? wsum[0] : 0;
  bucketBase[t] = off + incl - v;
  gCursorB[t]   = off + incl - v;
  if (t == 127) bucketBase[NBUCK] = off + incl;       // == N_EDGES
}

// pass1b: stage (src,dst) pairs grouped by bucket (contiguous per-block runs)
__global__ __launch_bounds__(256)
void pass1b_kernel(const int* __restrict__ src, const int* __restrict__ dst,
                   int* __restrict__ gCursorB, uint2* __restrict__ staging) {
  __shared__ int hist[NBUCK];
  if (threadIdx.x < NBUCK) hist[threadIdx.x] = 0;
  __syncthreads();
#pragma unroll
  for (int i = 0; i < 16; ++i) {
    int e = blockIdx.x * 4096 + i * 256 + threadIdx.x;
    if (e < N_EDGES) atomicAdd(&hist[dst[e] / NPB], 1);
  }
  __syncthreads();
  if (threadIdx.x < NBUCK)
    hist[threadIdx.x] = atomicAdd(&gCursorB[threadIdx.x], hist[threadIdx.x]);
  __syncthreads();
#pragma unroll
  for (int i = 0; i < 16; ++i) {
    int e = blockIdx.x * 4096 + i * 256 + threadIdx.x;
    if (e < N_EDGES) {
      int d = dst[e];
      int pos = atomicAdd(&hist[d / NPB], 1);     // LDS cursor
      staging[pos] = make_uint2((unsigned)src[e], (unsigned)d);
    }
  }
}

// pass2: one block per bucket (128 blocks). One node per thread (NPB=782<=1024).
__global__ __launch_bounds__(1024)
void pass2_kernel(const uint2* __restrict__ staging, const int* __restrict__ bucketBase,
                  int* __restrict__ start, float* __restrict__ invdeg,
                  int* __restrict__ esrc) {
  __shared__ int cnt[1024];
  __shared__ int cur[1024];
  __shared__ int wsum[16];
  const int b = blockIdx.x, tid = threadIdx.x;
  const int lane = tid & 63, wid = tid >> 6;
  const int n0 = b * NPB, n1 = min(n0 + NPB, N_NODES);
  const int nLocal = n1 - n0;
  const int p0 = bucketBase[b], p1 = bucketBase[b + 1];

  cnt[tid] = 0;
  __syncthreads();
  for (int e = p0 + tid; e < p1; e += 1024)
    atomicAdd(&cnt[staging[e].y - n0], 1);
  __syncthreads();

  int c = cnt[tid];
  int incl = wave_incl_scan(c, lane);
  if (lane == 63) wsum[wid] = incl;
  __syncthreads();
  if (wid == 0) {
    int v = (lane < 16) ? wsum[lane] : 0;
    int i2 = wave_incl_scan(v, lane);
    if (lane < 16) wsum[lane] = i2 - v;   // exclusive
  }
  __syncthreads();
  int excl = wsum[wid] + incl - c;
  cur[tid] = excl;
  if (tid < nLocal) {
    start[n0 + tid] = p0 + excl;
    invdeg[n0 + tid] = 1.0f / fmaxf((float)c, 1.0f);
  }
  if (b == NBUCK - 1 && tid == 0) start[N_NODES] = N_EDGES;
  __syncthreads();

  for (int e = p0 + tid; e < p1; e += 1024) {
    uint2 pr = staging[e];
    int pos = p0 + atomicAdd(&cur[pr.y - n0], 1);
    esrc[pos] = (int)pr.x;
  }
}

// ---------- gather-mean, 2 waves per node (edge-range split, LDS combine) ----------
template<int D>
__global__ __launch_bounds__(256)
void gather_mean(const unsigned short* __restrict__ h,
                 const int* __restrict__ start,
                 const int* __restrict__ esrc,
                 const float* __restrict__ invdeg,
                 unsigned short* __restrict__ hn) {
  constexpr int FPL = D / 64;           // 2 (D=128) or 4 (D=256)
  __shared__ float part[2][D];
  const int tid = threadIdx.x, wave = tid >> 6, lane = tid & 63;
  const int local = wave >> 1, sub = wave & 1;
  const int node = blockIdx.x * 2 + local;      // N_NODES even: no partial block
  const int s0 = start[node], s1 = start[node + 1];
  const int mid = s0 + ((s1 - s0 + 1) >> 1);
  int e = sub ? mid : s0;
  const int bnd = sub ? s1 : mid;
  float acc[FPL] = {};
  const unsigned short* base = h + lane * FPL;

  if constexpr (FPL == 4) {
    for (; e + 4 <= bnd; e += 4) {
      int sn0 = esrc[e], sn1 = esrc[e + 1], sn2 = esrc[e + 2], sn3 = esrc[e + 3];
      uint2 p0 = *(const uint2*)(base + (size_t)sn0 * D);
      uint2 p1 = *(const uint2*)(base + (size_t)sn1 * D);
      uint2 p2 = *(const uint2*)(base + (size_t)sn2 * D);
      uint2 p3 = *(const uint2*)(base + (size_t)sn3 * D);
      acc[0] += bf_lo(p0.x) + bf_lo(p1.x) + bf_lo(p2.x) + bf_lo(p3.x);
      acc[1] += bf_hi(p0.x) + bf_hi(p1.x) + bf_hi(p2.x) + bf_hi(p3.x);
      acc[2] += bf_lo(p0.y) + bf_lo(p1.y) + bf_lo(p2.y) + bf_lo(p3.y);
      acc[3] += bf_hi(p0.y) + bf_hi(p1.y) + bf_hi(p2.y) + bf_hi(p3.y);
    }
    for (; e < bnd; ++e) {
      int sn = esrc[e];
      uint2 p = *(const uint2*)(base + (size_t)sn * D);
      acc[0] += bf_lo(p.x); acc[1] += bf_hi(p.x);
      acc[2] += bf_lo(p.y); acc[3] += bf_hi(p.y);
    }
  } else {
    for (; e + 4 <= bnd; e += 4) {
      int sn0 = esrc[e], sn1 = esrc[e + 1], sn2 = esrc[e + 2], sn3 = esrc[e + 3];
      unsigned int p0 = *(const unsigned int*)(base + (size_t)sn0 * D);
      unsigned int p1 = *(const unsigned int*)(base + (size_t)sn1 * D);
      unsigned int p2 = *(const unsigned int*)(base + (size_t)sn2 * D);
      unsigned int p3 = *(const unsigned int*)(base + (size_t)sn3 * D);
      acc[0] += bf_lo(p0) + bf_lo(p1) + bf_lo(p2) + bf_lo(p3);
      acc[1] += bf_hi(p0) + bf_hi(p1) + bf_hi(p2) + bf_hi(p3);
    }
    for (; e < bnd; ++e) {
      int sn = esrc[e];
      unsigned int p = *(const unsigned int*)(base + (size_t)sn * D);
      acc[0] += bf_lo(p); acc[1] += bf_hi(p);
    }
  }

  if (sub == 1) {
    if constexpr (FPL == 4)
      *(float4*)&part[local][lane * 4] = make_float4(acc[0], acc[1], acc[2], acc[3]);
    else
      *(float2*)&part[local][lane * 2] = make_float2(acc[0], acc[1]);
  }
  __syncthreads();
  if (sub == 0) {
    float inv = invdeg[node];
    unsigned short* out = hn + (size_t)node * D + lane * FPL;
    if constexpr (FPL == 4) {
      float4 p = *(const float4*)&part[local][lane * 4];
      ushort4 o;
      o.x = f2bf((acc[0] + p.x) * inv); o.y = f2bf((acc[1] + p.y) * inv);
      o.z = f2bf((acc[2] + p.z) * inv); o.w = f2bf((acc[3] + p.w) * inv);
      *(ushort4*)out = o;
    } else {
      float2 p = *(const float2*)&part[local][lane * 2];
      ushort2 o;
      o.x = f2bf((acc[0] + p.x) * inv); o.y = f2bf((acc[1] + p.y) * inv);
      *(ushort2*)out = o;
    }
  }
}

// ---------- gather_add64: out[n,:] += invdeg * sum of Y3[src,:] (64 fp32 cols) ----
// 2 waves per node; within a wave, half-wave per edge (lane covers 2 feats).
__global__ __launch_bounds__(256)
void gather_add64(const unsigned short* __restrict__ Y3,
                  const int* __restrict__ start, const int* __restrict__ esrc,
                  const float* __restrict__ invdeg, float* __restrict__ out) {
  __shared__ float part[2][64];
  const int tid = threadIdx.x, wave = tid >> 6, lane = tid & 63;
  const int local = wave >> 1, sub = wave & 1;
  const int node = blockIdx.x * 2 + local;
  const int half = lane >> 5, l32 = lane & 31;
  const int s0 = start[node], s1 = start[node + 1];
  const int mid = s0 + ((s1 - s0 + 1) >> 1);
  const int a = sub ? mid : s0, bnd = sub ? s1 : mid;
  float a0 = 0.f, a1 = 0.f;
  for (int e = a + half; e < bnd; e += 2) {
    int sn = esrc[e];
    unsigned int p = *(const unsigned int*)(Y3 + (size_t)sn * 64 + 2 * l32);
    a0 += bf_lo(p); a1 += bf_hi(p);
  }
  a0 += __shfl_xor(a0, 32, 64);
  a1 += __shfl_xor(a1, 32, 64);
  if (sub == 1 && half == 0) {
    part[local][2 * l32] = a0; part[local][2 * l32 + 1] = a1;
  }
  __syncthreads();
  if (sub == 0 && half == 0) {
    float inv = invdeg[node];
    float2* q = (float2*)(out + (size_t)node * 64 + 2 * l32);
    float2 v = *q;
    v.x += inv * (a0 + part[local][2 * l32]);
    v.y += inv * (a1 + part[local][2 * l32 + 1]);
    *q = v;
  }
}

// ---------- LDS double-buffered fused GEMM ----------
// MODE 0: out = [H | HN] @ Wb^T + bias (optional relu), K = 2D.
// MODE 1: K = D (reads H only), Wb is 128 x D (rows 0-63 self, 64-127 neigh);
//         cols 0-63 -> d_out fp32 (+bias), cols 64-127 -> Y3 bf16.
template<int D, int DOUT, int BN, bool RELU, bool OUTF32, int MODE>
__global__ __launch_bounds__(256)
void sage_gemm(const unsigned short* __restrict__ H,
               const unsigned short* __restrict__ HN,
               const unsigned short* __restrict__ Wb,
               const float* __restrict__ bias,
               void* __restrict__ outp,
               unsigned short* __restrict__ y3) {
  constexpr int K   = (MODE == 1) ? D : 2 * D;
  constexpr int BM  = 128, KC = 32;
  constexpr int NCHUNK = K / KC;
  constexpr int AF  = BM / 16;
  constexpr int BF  = BN / 16;
  constexpr int FR  = AF + BF;
  constexpr int NMF = 4;
  constexpr int NJF = BF / 2;

  __shared__ __align__(16) unsigned short lds0[FR * 512];
  __shared__ __align__(16) unsigned short lds1[FR * 512];

  const int tid  = threadIdx.x;
  const int wave = tid >> 6, lane = tid & 63;
  const int l16  = lane & 15, quad = lane >> 4;
  const int n0   = blockIdx.x * BM;
  const int bn0  = blockIdx.y * BN;
  const int wm   = wave >> 1, wn = wave & 1;

  floatx4 acc[NMF][NJF] = {};

  auto stage = [&](int c, unsigned short* buf) {
    const int kc = c * KC;
    const unsigned short* srcH = (kc < D) ? H : HN;
    const int kb = (kc < D) ? kc : kc - D;
    const int w0 = __builtin_amdgcn_readfirstlane(wave);
#pragma unroll
    for (int i = 0; i < FR / 4; ++i) {
      const int fu = w0 + 4 * i;
      const unsigned short* g;
      if (fu < AF) {
        int row = min(n0 + fu * 16 + l16, N_NODES - 1);
        g = srcH + (size_t)row * D + kb + quad * 8;
      } else {
        int col = bn0 + (fu - AF) * 16 + l16;
        g = Wb + (size_t)col * K + kc + quad * 8;
      }
      __builtin_amdgcn_global_load_lds(
          (const __attribute__((address_space(1))) unsigned int*)g,
          (__attribute__((address_space(3))) unsigned int*)(buf + fu * 512),
          16, 0, 0);
    }
  };

  auto compute = [&](const unsigned short* buf) {
    short8 b[NJF];
#pragma unroll
    for (int jt = 0; jt < NJF; ++jt)
      b[jt] = *(const short8*)(buf + (AF + wn * NJF + jt) * 512 + lane * 8);
#pragma unroll
    for (int mi = 0; mi < NMF; ++mi) {
      short8 a = *(const short8*)(buf + (wm * NMF + mi) * 512 + lane * 8);
#pragma unroll
      for (int jt = 0; jt < NJF; ++jt)
        acc[mi][jt] = __builtin_amdgcn_mfma_f32_16x16x32_bf16(a, b[jt], acc[mi][jt], 0, 0, 0);
    }
  };

  stage(0, lds0);
  __syncthreads();
#pragma unroll 1
  for (int c = 0; c < NCHUNK; c += 2) {
    stage(c + 1, lds1);
    compute(lds0);
    __syncthreads();
    if (c + 2 < NCHUNK) stage(c + 2, lds0);
    compute(lds1);
    __syncthreads();
  }

#pragma unroll
  for (int mi = 0; mi < NMF; ++mi) {
#pragma unroll
    for (int jt = 0; jt < NJF; ++jt) {
      int j = bn0 + wn * (NJF * 16) + jt * 16 + l16;
      float bj = (MODE == 1 && wn == 1) ? 0.0f : bias[j];
#pragma unroll
      for (int r = 0; r < 4; ++r) {
        int node = n0 + wm * 64 + mi * 16 + quad * 4 + r;
        if (node < N_NODES) {
          float v = acc[mi][jt][r];
          if constexpr (MODE == 1) {
            if (wn == 0) ((float*)outp)[(size_t)node * 64 + j] = v + bj;
            else y3[(size_t)node * 64 + (j - 64)] = f2bf(v);
          } else {
            v += bj;
            if (RELU) v = fmaxf(v, 0.0f);
            if (OUTF32) ((float*)outp)[(size_t)node * DOUT + j] = v;
            else ((unsigned short*)outp)[(size_t)node * DOUT + j] = f2bf(v);
          }
        }
      }
    }
  }
}

extern "C" void kernel_launch(void* const* d_in, const int* in_sizes, int n_in,
                              void* d_out, int out_size, void* d_ws, size_t ws_size,
                              hipStream_t stream) {
  const float* x   = (const float*)d_in[0];
  const int*   src = (const int*)d_in[1];
  const int*   dst = (const int*)d_in[2];
  const float* W1 = (const float*)d_in[3];
  const float* b1 = (const float*)d_in[4];
  const float* W2 = (const float*)d_in[5];
  const float* b2 = (const float*)d_in[6];
  const float* W3 = (const float*)d_in[7];
  const float* b3 = (const float*)d_in[8];

  char* ws = (char*)d_ws;
  unsigned short* H0 = (unsigned short*)ws; ws += (size_t)N_NODES * 128 * 2; // 25.6 MB
  unsigned short* H1 = (unsigned short*)ws; ws += (size_t)N_NODES * 256 * 2; // 51.2 MB
  unsigned short* H2 = (unsigned short*)ws; ws += (size_t)N_NODES * 256 * 2; // 51.2 MB
  unsigned short* HN = (unsigned short*)ws; ws += (size_t)N_NODES * 256 * 2; // 51.2 MB
  uint2* staging = (uint2*)ws; ws += (size_t)N_EDGES * 8;                    // 12.8 MB
  int* esrc   = (int*)ws;  ws += (size_t)N_EDGES * 4;                        // 6.4 MB
  int* startp = (int*)ws;  ws += (size_t)(N_NODES + 32) * 4;
  float* invdeg = (float*)ws; ws += (size_t)(N_NODES + 32) * 4;
  int* bucketCount = (int*)ws; ws += 512;    // NBUCK ints (R7 bug: was 256 B)
  int* bucketBase  = (int*)ws; ws += 1024;   // NBUCK+1 ints (R7 bug: was 512 B, [128] overflowed)
  int* gCursorB    = (int*)ws; ws += 512;    // NBUCK ints (R7 bug: was 256 B)
  unsigned short* Y3 = (unsigned short*)ws; ws += (size_t)N_NODES * 64 * 2;  // 12.8 MB
  unsigned short* Wb1 = (unsigned short*)ws; ws += 256 * 256 * 2;
  unsigned short* Wb2 = (unsigned short*)ws; ws += 256 * 512 * 2;
  unsigned short* Wb3 = (unsigned short*)ws; ws += 128 * 256 * 2;

  // CSR build: bucketed counting sort (shared by all 3 layers)
  hipMemsetAsync(bucketCount, 0, NBUCK * 4, stream);
  pass1a_kernel<<<NB_E, 256, 0, stream>>>(dst, bucketCount);
  scanB_kernel<<<1, 128, 0, stream>>>(bucketCount, bucketBase, gCursorB);
  pass1b_kernel<<<NB_E, 256, 0, stream>>>(src, dst, gCursorB, staging);
  pass2_kernel<<<NBUCK, 1024, 0, stream>>>(staging, bucketBase, startp, invdeg, esrc);

  // conversions to bf16
  cvt_f32_bf16<<<(N_NODES * 128 / 4 + 255) / 256, 256, 0, stream>>>(x, H0, N_NODES * 128 / 4);
  cvt_f32_bf16<<<(256 * 256 / 4 + 255) / 256, 256, 0, stream>>>(W1, Wb1, 256 * 256 / 4);
  cvt_f32_bf16<<<(256 * 512 / 4 + 255) / 256, 256, 0, stream>>>(W2, Wb2, 256 * 512 / 4);
  cvt_w3cat<<<(128 * 256 / 4 + 255) / 256, 256, 0, stream>>>(W3, Wb3);

  const int GGRID2 = N_NODES / 2;                  // 2 nodes per block (4 waves)
  const int MG = (N_NODES + 127) / 128;            // 782 M-tiles

  // ---- layer 1: D=128 -> 256, relu ----
  gather_mean<128><<<GGRID2, 256, 0, stream>>>(H0, startp, esrc, invdeg, HN);
  sage_gemm<128, 256, 128, true, false, 0><<<dim3(MG, 2), 256, 0, stream>>>(H0, HN, Wb1, b1, H1, nullptr);

  // ---- layer 2: D=256 -> 256, relu ----
  gather_mean<256><<<GGRID2, 256, 0, stream>>>(H1, startp, esrc, invdeg, HN);
  sage_gemm<256, 256, 128, true, false, 0><<<dim3(MG, 2), 256, 0, stream>>>(H1, HN, Wb2, b2, H2, nullptr);

  // ---- layer 3 (aggregate after GEMM): dual GEMM then edge-mean on 64 cols ----
  sage_gemm<256, 128, 128, false, true, 1><<<dim3(MG, 1), 256, 0, stream>>>(H2, nullptr, Wb3, b3, (float*)d_out, Y3);
  gather_add64<<<GGRID2, 256, 0, stream>>>(Y3, startp, esrc, invdeg, (float*)d_out);
}

// Round 9
// 616.414 us; speedup vs baseline: 1.0668x; 1.0668x over previous
//
#include <hip/hip_runtime.h>
#include <hip/hip_bf16.h>
#include <cstdint>
#include <cstddef>

#define N_NODES 100000
#define N_EDGES 1600000
#define NBUCK   128
#define NPB     782           // nodes per bucket; 128*782 = 100096 >= N_NODES
#define NB_E    ((N_EDGES + 4095) / 4096)   // 391 blocks, 4096 edges each
// staging pack: src (17 bits, <131072) | localdst (10 bits, <782) << 17

typedef __attribute__((ext_vector_type(8))) short short8;
typedef __attribute__((ext_vector_type(4))) float floatx4;

__device__ inline float bf_lo(unsigned int u) { return __uint_as_float(u << 16); }
__device__ inline float bf_hi(unsigned int u) { return __uint_as_float(u & 0xffff0000u); }
__device__ inline unsigned short f2bf(float f) {
  unsigned int u = __float_as_uint(f);
  u += 0x7fffu + ((u >> 16) & 1u);   // round-nearest-even
  return (unsigned short)(u >> 16);
}

// ---------- fp32 -> bf16 conversion, 4 elems/thread ----------
__global__ void cvt_f32_bf16(const float* __restrict__ in,
                             unsigned short* __restrict__ out, int n4) {
  int t = blockIdx.x * blockDim.x + threadIdx.x;
  if (t >= n4) return;
  float4 v = ((const float4*)in)[t];
  ushort4 o;
  o.x = f2bf(v.x); o.y = f2bf(v.y); o.z = f2bf(v.z); o.w = f2bf(v.w);
  ((ushort4*)out)[t] = o;
}

// W3 (64 x 512 fp32) -> Wcat (128 x 256 bf16): rows 0-63 = self cols, 64-127 = neigh cols
__global__ void cvt_w3cat(const float* __restrict__ W3, unsigned short* __restrict__ out) {
  int t = blockIdx.x * blockDim.x + threadIdx.x;      // 128*256/4 = 8192 threads
  if (t >= 128 * 256 / 4) return;
  int idx4 = t * 4;
  int r = idx4 >> 8, c = idx4 & 255;
  float4 v = *(const float4*)(W3 + (size_t)(r & 63) * 512 + (r >> 6) * 256 + c);
  ushort4 o;
  o.x = f2bf(v.x); o.y = f2bf(v.y); o.z = f2bf(v.z); o.w = f2bf(v.w);
  *(ushort4*)(out + (size_t)r * 256 + c) = o;
}

__device__ inline int wave_incl_scan(int v, int lane) {
#pragma unroll
  for (int off = 1; off < 64; off <<= 1) {
    int t = __shfl_up(v, off, 64);
    if (lane >= off) v += t;
  }
  return v;
}

// ---------- CSR build: bucketed counting sort (no device-scope scatter) ----------
__global__ __launch_bounds__(256)
void pass1a_kernel(const int* __restrict__ dst, int* __restrict__ bucketCount) {
  __shared__ int hist[NBUCK];
  if (threadIdx.x < NBUCK) hist[threadIdx.x] = 0;
  __syncthreads();
#pragma unroll
  for (int i = 0; i < 16; ++i) {
    int e = blockIdx.x * 4096 + i * 256 + threadIdx.x;
    if (e < N_EDGES) atomicAdd(&hist[dst[e] / NPB], 1);
  }
  __syncthreads();
  if (threadIdx.x < NBUCK) atomicAdd(&bucketCount[threadIdx.x], hist[threadIdx.x]);
}

// scanB: exclusive scan of 128 bucket counts (2 waves)
__global__ void scanB_kernel(const int* __restrict__ bucketCount,
                             int* __restrict__ bucketBase, int* __restrict__ gCursorB) {
  __shared__ int wsum[2];
  int t = threadIdx.x, lane = t & 63, wid = t >> 6;   // 128 threads
  int v = bucketCount[t];
  int incl = wave_incl_scan(v, lane);
  if (lane == 63) wsum[wid] = incl;
  __syncthreads();
  int off = (wid == 1) ? wsum[0] : 0;
  bucketBase[t] = off + incl - v;
  gCursorB[t]   = off + incl - v;
  if (t == 127) bucketBase[NBUCK] = off + incl;       // == N_EDGES
}

// pass1b: stage packed (src|localdst) grouped by bucket (contiguous per-block runs)
__global__ __launch_bounds__(256)
void pass1b_kernel(const int* __restrict__ src, const int* __restrict__ dst,
                   int* __restrict__ gCursorB, unsigned int* __restrict__ staging) {
  __shared__ int hist[NBUCK];
  if (threadIdx.x < NBUCK) hist[threadIdx.x] = 0;
  __syncthreads();
#pragma unroll
  for (int i = 0; i < 16; ++i) {
    int e = blockIdx.x * 4096 + i * 256 + threadIdx.x;
    if (e < N_EDGES) atomicAdd(&hist[dst[e] / NPB], 1);
  }
  __syncthreads();
  if (threadIdx.x < NBUCK)
    hist[threadIdx.x] = atomicAdd(&gCursorB[threadIdx.x], hist[threadIdx.x]);
  __syncthreads();
#pragma unroll
  for (int i = 0; i < 16; ++i) {
    int e = blockIdx.x * 4096 + i * 256 + threadIdx.x;
    if (e < N_EDGES) {
      int d = dst[e];
      int b = d / NPB;
      int pos = atomicAdd(&hist[b], 1);           // LDS cursor
      staging[pos] = (unsigned)src[e] | ((unsigned)(d - b * NPB) << 17);
    }
  }
}

// pass2: one block per bucket (128 blocks). One node per thread (NPB=782<=1024).
__global__ __launch_bounds__(1024)
void pass2_kernel(const unsigned int* __restrict__ staging, const int* __restrict__ bucketBase,
                  int* __restrict__ start, float* __restrict__ invdeg,
                  int* __restrict__ esrc) {
  __shared__ int cnt[1024];
  __shared__ int cur[1024];
  __shared__ int wsum[16];
  const int b = blockIdx.x, tid = threadIdx.x;
  const int lane = tid & 63, wid = tid >> 6;
  const int n0 = b * NPB, n1 = min(n0 + NPB, N_NODES);
  const int nLocal = n1 - n0;
  const int p0 = bucketBase[b], p1 = bucketBase[b + 1];

  cnt[tid] = 0;
  __syncthreads();
  for (int e = p0 + tid; e < p1; e += 1024)
    atomicAdd(&cnt[staging[e] >> 17], 1);
  __syncthreads();

  int c = cnt[tid];
  int incl = wave_incl_scan(c, lane);
  if (lane == 63) wsum[wid] = incl;
  __syncthreads();
  if (wid == 0) {
    int v = (lane < 16) ? wsum[lane] : 0;
    int i2 = wave_incl_scan(v, lane);
    if (lane < 16) wsum[lane] = i2 - v;   // exclusive
  }
  __syncthreads();
  int excl = wsum[wid] + incl - c;
  cur[tid] = excl;
  if (tid < nLocal) {
    start[n0 + tid] = p0 + excl;
    invdeg[n0 + tid] = 1.0f / fmaxf((float)c, 1.0f);
  }
  if (b == NBUCK - 1 && tid == 0) start[N_NODES] = N_EDGES;
  __syncthreads();

  for (int e = p0 + tid; e < p1; e += 1024) {
    unsigned int pr = staging[e];
    int pos = p0 + atomicAdd(&cur[pr >> 17], 1);
    esrc[pos] = (int)(pr & 0x1FFFFu);
  }
}

// ---------- gather-mean: hn[n] = mean over incoming edges of h[src] ----------
// One wave per dst node (R6 form — R8's 2-wave split regressed: the gather is
// fabric-bound at ~3.8 TB/s beyond-L2, not latency-bound; extra MLP just queues).
template<int D>
__global__ __launch_bounds__(256)
void gather_mean(const unsigned short* __restrict__ h,
                 const int* __restrict__ start,
                 const int* __restrict__ esrc,
                 const float* __restrict__ invdeg,
                 unsigned short* __restrict__ hn) {
  int wave = (int)((blockIdx.x * 256 + threadIdx.x) >> 6);
  if (wave >= N_NODES) return;
  int lane = threadIdx.x & 63;
  int s0 = start[wave], s1 = start[wave + 1];
  constexpr int FPL = D / 64;           // 2 (D=128) or 4 (D=256)
  float acc[FPL] = {};
  const unsigned short* base = h + lane * FPL;

  int e = s0;
  if constexpr (FPL == 4) {
    for (; e + 4 <= s1; e += 4) {
      int sn0 = esrc[e], sn1 = esrc[e + 1], sn2 = esrc[e + 2], sn3 = esrc[e + 3];
      uint2 p0 = *(const uint2*)(base + (size_t)sn0 * D);
      uint2 p1 = *(const uint2*)(base + (size_t)sn1 * D);
      uint2 p2 = *(const uint2*)(base + (size_t)sn2 * D);
      uint2 p3 = *(const uint2*)(base + (size_t)sn3 * D);
      acc[0] += bf_lo(p0.x) + bf_lo(p1.x) + bf_lo(p2.x) + bf_lo(p3.x);
      acc[1] += bf_hi(p0.x) + bf_hi(p1.x) + bf_hi(p2.x) + bf_hi(p3.x);
      acc[2] += bf_lo(p0.y) + bf_lo(p1.y) + bf_lo(p2.y) + bf_lo(p3.y);
      acc[3] += bf_hi(p0.y) + bf_hi(p1.y) + bf_hi(p2.y) + bf_hi(p3.y);
    }
    for (; e < s1; ++e) {
      int sn = esrc[e];
      uint2 p = *(const uint2*)(base + (size_t)sn * D);
      acc[0] += bf_lo(p.x); acc[1] += bf_hi(p.x);
      acc[2] += bf_lo(p.y); acc[3] += bf_hi(p.y);
    }
  } else {
    for (; e + 4 <= s1; e += 4) {
      int sn0 = esrc[e], sn1 = esrc[e + 1], sn2 = esrc[e + 2], sn3 = esrc[e + 3];
      unsigned int p0 = *(const unsigned int*)(base + (size_t)sn0 * D);
      unsigned int p1 = *(const unsigned int*)(base + (size_t)sn1 * D);
      unsigned int p2 = *(const unsigned int*)(base + (size_t)sn2 * D);
      unsigned int p3 = *(const unsigned int*)(base + (size_t)sn3 * D);
      acc[0] += bf_lo(p0) + bf_lo(p1) + bf_lo(p2) + bf_lo(p3);
      acc[1] += bf_hi(p0) + bf_hi(p1) + bf_hi(p2) + bf_hi(p3);
    }
    for (; e < s1; ++e) {
      int sn = esrc[e];
      unsigned int p = *(const unsigned int*)(base + (size_t)sn * D);
      acc[0] += bf_lo(p); acc[1] += bf_hi(p);
    }
  }

  float inv = invdeg[wave];
  unsigned short* out = hn + (size_t)wave * D + lane * FPL;
  if constexpr (FPL == 4) {
    ushort4 o;
    o.x = f2bf(acc[0] * inv); o.y = f2bf(acc[1] * inv);
    o.z = f2bf(acc[2] * inv); o.w = f2bf(acc[3] * inv);
    *(ushort4*)out = o;
  } else {
    ushort2 o;
    o.x = f2bf(acc[0] * inv); o.y = f2bf(acc[1] * inv);
    *(ushort2*)out = o;
  }
}

// ---------- gather_add64: out[n,:] += invdeg * sum of Y3[src,:]  (64 fp32 cols) ----
// One wave per node; half-wave per edge (lane covers 2 feats). R6 form.
__global__ __launch_bounds__(256)
void gather_add64(const unsigned short* __restrict__ Y3,
                  const int* __restrict__ start, const int* __restrict__ esrc,
                  const float* __restrict__ invdeg, float* __restrict__ out) {
  int wave = (int)((blockIdx.x * 256 + threadIdx.x) >> 6);
  if (wave >= N_NODES) return;
  int lane = threadIdx.x & 63;
  int half = lane >> 5, l32 = lane & 31;
  int s0 = start[wave], s1 = start[wave + 1];
  float a0 = 0.f, a1 = 0.f;
  for (int e = s0 + half; e < s1; e += 2) {
    int sn = esrc[e];
    unsigned int p = *(const unsigned int*)(Y3 + (size_t)sn * 64 + 2 * l32);
    a0 += bf_lo(p); a1 += bf_hi(p);
  }
  a0 += __shfl_xor(a0, 32, 64);
  a1 += __shfl_xor(a1, 32, 64);
  if (half == 0) {
    float inv = invdeg[wave];
    float2* q = (float2*)(out + (size_t)wave * 64 + 2 * l32);
    float2 v = *q;
    v.x += inv * a0; v.y += inv * a1;
    *q = v;
  }
}

// ---------- LDS double-buffered fused GEMM ----------
// MODE 0: out = [H | HN] @ Wb^T + bias (optional relu), K = 2D.
// MODE 1: K = D (reads H only), Wb is 128 x D (rows 0-63 self, 64-127 neigh);
//         cols 0-63 -> d_out fp32 (+bias), cols 64-127 -> Y3 bf16.
template<int D, int DOUT, int BN, bool RELU, bool OUTF32, int MODE>
__global__ __launch_bounds__(256)
void sage_gemm(const unsigned short* __restrict__ H,
               const unsigned short* __restrict__ HN,
               const unsigned short* __restrict__ Wb,
               const float* __restrict__ bias,
               void* __restrict__ outp,
               unsigned short* __restrict__ y3) {
  constexpr int K   = (MODE == 1) ? D : 2 * D;
  constexpr int BM  = 128, KC = 32;
  constexpr int NCHUNK = K / KC;
  constexpr int AF  = BM / 16;
  constexpr int BF  = BN / 16;
  constexpr int FR  = AF + BF;
  constexpr int NMF = 4;
  constexpr int NJF = BF / 2;

  __shared__ __align__(16) unsigned short lds0[FR * 512];
  __shared__ __align__(16) unsigned short lds1[FR * 512];

  const int tid  = threadIdx.x;
  const int wave = tid >> 6, lane = tid & 63;
  const int l16  = lane & 15, quad = lane >> 4;
  const int n0   = blockIdx.x * BM;
  const int bn0  = blockIdx.y * BN;
  const int wm   = wave >> 1, wn = wave & 1;

  floatx4 acc[NMF][NJF] = {};

  auto stage = [&](int c, unsigned short* buf) {
    const int kc = c * KC;
    const unsigned short* srcH = (kc < D) ? H : HN;
    const int kb = (kc < D) ? kc : kc - D;
    const int w0 = __builtin_amdgcn_readfirstlane(wave);
#pragma unroll
    for (int i = 0; i < FR / 4; ++i) {
      const int fu = w0 + 4 * i;
      const unsigned short* g;
      if (fu < AF) {
        int row = min(n0 + fu * 16 + l16, N_NODES - 1);
        g = srcH + (size_t)row * D + kb + quad * 8;
      } else {
        int col = bn0 + (fu - AF) * 16 + l16;
        g = Wb + (size_t)col * K + kc + quad * 8;
      }
      __builtin_amdgcn_global_load_lds(
          (const __attribute__((address_space(1))) unsigned int*)g,
          (__attribute__((address_space(3))) unsigned int*)(buf + fu * 512),
          16, 0, 0);
    }
  };

  auto compute = [&](const unsigned short* buf) {
    short8 b[NJF];
#pragma unroll
    for (int jt = 0; jt < NJF; ++jt)
      b[jt] = *(const short8*)(buf + (AF + wn * NJF + jt) * 512 + lane * 8);
#pragma unroll
    for (int mi = 0; mi < NMF; ++mi) {
      short8 a = *(const short8*)(buf + (wm * NMF + mi) * 512 + lane * 8);
#pragma unroll
      for (int jt = 0; jt < NJF; ++jt)
        acc[mi][jt] = __builtin_amdgcn_mfma_f32_16x16x32_bf16(a, b[jt], acc[mi][jt], 0, 0, 0);
    }
  };

  stage(0, lds0);
  __syncthreads();
#pragma unroll 1
  for (int c = 0; c < NCHUNK; c += 2) {
    stage(c + 1, lds1);
    compute(lds0);
    __syncthreads();
    if (c + 2 < NCHUNK) stage(c + 2, lds0);
    compute(lds1);
    __syncthreads();
  }

#pragma unroll
  for (int mi = 0; mi < NMF; ++mi) {
#pragma unroll
    for (int jt = 0; jt < NJF; ++jt) {
      int j = bn0 + wn * (NJF * 16) + jt * 16 + l16;
      float bj = (MODE == 1 && wn == 1) ? 0.0f : bias[j];
#pragma unroll
      for (int r = 0; r < 4; ++r) {
        int node = n0 + wm * 64 + mi * 16 + quad * 4 + r;
        if (node < N_NODES) {
          float v = acc[mi][jt][r];
          if constexpr (MODE == 1) {
            if (wn == 0) ((float*)outp)[(size_t)node * 64 + j] = v + bj;
            else y3[(size_t)node * 64 + (j - 64)] = f2bf(v);
          } else {
            v += bj;
            if (RELU) v = fmaxf(v, 0.0f);
            if (OUTF32) ((float*)outp)[(size_t)node * DOUT + j] = v;
            else ((unsigned short*)outp)[(size_t)node * DOUT + j] = f2bf(v);
          }
        }
      }
    }
  }
}

extern "C" void kernel_launch(void* const* d_in, const int* in_sizes, int n_in,
                              void* d_out, int out_size, void* d_ws, size_t ws_size,
                              hipStream_t stream) {
  const float* x   = (const float*)d_in[0];
  const int*   src = (const int*)d_in[1];
  const int*   dst = (const int*)d_in[2];
  const float* W1 = (const float*)d_in[3];
  const float* b1 = (const float*)d_in[4];
  const float* W2 = (const float*)d_in[5];
  const float* b2 = (const float*)d_in[6];
  const float* W3 = (const float*)d_in[7];
  const float* b3 = (const float*)d_in[8];

  char* ws = (char*)d_ws;
  unsigned short* H0 = (unsigned short*)ws; ws += (size_t)N_NODES * 128 * 2; // 25.6 MB
  unsigned short* H1 = (unsigned short*)ws; ws += (size_t)N_NODES * 256 * 2; // 51.2 MB
  unsigned short* H2 = (unsigned short*)ws; ws += (size_t)N_NODES * 256 * 2; // 51.2 MB
  unsigned short* HN = (unsigned short*)ws; ws += (size_t)N_NODES * 256 * 2; // 51.2 MB
  unsigned int* staging = (unsigned int*)ws; ws += (size_t)N_EDGES * 4;      // 6.4 MB (packed)
  int* esrc   = (int*)ws;  ws += (size_t)N_EDGES * 4;                        // 6.4 MB
  int* startp = (int*)ws;  ws += (size_t)(N_NODES + 32) * 4;
  float* invdeg = (float*)ws; ws += (size_t)(N_NODES + 32) * 4;
  int* bucketCount = (int*)ws; ws += 512;    // NBUCK ints
  int* bucketBase  = (int*)ws; ws += 1024;   // NBUCK+1 ints
  int* gCursorB    = (int*)ws; ws += 512;    // NBUCK ints
  unsigned short* Y3 = (unsigned short*)ws; ws += (size_t)N_NODES * 64 * 2;  // 12.8 MB
  unsigned short* Wb1 = (unsigned short*)ws; ws += 256 * 256 * 2;
  unsigned short* Wb2 = (unsigned short*)ws; ws += 256 * 512 * 2;
  unsigned short* Wb3 = (unsigned short*)ws; ws += 128 * 256 * 2;

  // CSR build: bucketed counting sort (shared by all 3 layers)
  hipMemsetAsync(bucketCount, 0, NBUCK * 4, stream);
  pass1a_kernel<<<NB_E, 256, 0, stream>>>(dst, bucketCount);
  scanB_kernel<<<1, 128, 0, stream>>>(bucketCount, bucketBase, gCursorB);
  pass1b_kernel<<<NB_E, 256, 0, stream>>>(src, dst, gCursorB, staging);
  pass2_kernel<<<NBUCK, 1024, 0, stream>>>(staging, bucketBase, startp, invdeg, esrc);

  // conversions to bf16
  cvt_f32_bf16<<<(N_NODES * 128 / 4 + 255) / 256, 256, 0, stream>>>(x, H0, N_NODES * 128 / 4);
  cvt_f32_bf16<<<(256 * 256 / 4 + 255) / 256, 256, 0, stream>>>(W1, Wb1, 256 * 256 / 4);
  cvt_f32_bf16<<<(256 * 512 / 4 + 255) / 256, 256, 0, stream>>>(W2, Wb2, 256 * 512 / 4);
  cvt_w3cat<<<(128 * 256 / 4 + 255) / 256, 256, 0, stream>>>(W3, Wb3);

  const int GGRID = (N_NODES * 64 + 255) / 256;    // one wave per node
  const int MG = (N_NODES + 127) / 128;            // 782 M-tiles

  // ---- layer 1: D=128 -> 256, relu ----
  gather_mean<128><<<GGRID, 256, 0, stream>>>(H0, startp, esrc, invdeg, HN);
  sage_gemm<128, 256, 128, true, false, 0><<<dim3(MG, 2), 256, 0, stream>>>(H0, HN, Wb1, b1, H1, nullptr);

  // ---- layer 2: D=256 -> 256, relu ----
  gather_mean<256><<<GGRID, 256, 0, stream>>>(H1, startp, esrc, invdeg, HN);
  sage_gemm<256, 256, 128, true, false, 0><<<dim3(MG, 2), 256, 0, stream>>>(H1, HN, Wb2, b2, H2, nullptr);

  // ---- layer 3 (aggregate after GEMM): dual GEMM then edge-mean on 64 cols ----
  sage_gemm<256, 128, 128, false, true, 1><<<dim3(MG, 1), 256, 0, stream>>>(H2, nullptr, Wb3, b3, (float*)d_out, Y3);
  gather_add64<<<GGRID, 256, 0, stream>>>(Y3, startp, esrc, invdeg, (float*)d_out);
}